// Round 1
// baseline (418.516 us; speedup 1.0000x reference)
//
#include <hip/hip_runtime.h>
#include <hip/hip_bf16.h>

// Problem constants (FEDformerEncoder): BS=32 CNT=128 W=2048 P=1024 E=8 K=25 L=2
#define BSZ 32
#define CNTS 128
#define WD 2048
#define PD 1024
#define ED 8
#define KSZ 25
#define LN 2
#define MROWS (BSZ*CNTS)   // 4096
#define QKVN (3*PD)        // 3072
#define NWL (PD*WD)        // 2M elements per weight tensor per layer

typedef _Float16 f16;
typedef __attribute__((ext_vector_type(8))) _Float16 f16x8;  // 8 f16 = 4 VGPRs
typedef __attribute__((ext_vector_type(4))) float f32x4;
typedef __attribute__((ext_vector_type(2))) float f32x2;

#define PI_F 3.14159265358979323846f
// LDS physical index padding for the FFT (+1 float2 per 32 elements)
#define PAD(a) ((a) + ((a) >> 5))

// ---------------------------------------------------------------------------
// Per-layer weight conversion, one dispatch: wq|wk|wv -> wqkv16 packed, wo -> wo16.
// ---------------------------------------------------------------------------
__global__ __launch_bounds__(256) void cvt_layer(
    const float* __restrict__ wq, const float* __restrict__ wk,
    const float* __restrict__ wv, const float* __restrict__ wo,
    f16* __restrict__ wqkv16, f16* __restrict__ wo16)
{
    const int i = (blockIdx.x * 256 + threadIdx.x) * 4;
    const float* src;
    f16* dst;
    if (i < 3*NWL) {
        dst = wqkv16 + i;
        src = (i < NWL) ? wq + i : (i < 2*NWL) ? wk + (i - NWL) : wv + (i - 2*NWL);
    } else {
        dst = wo16 + (i - 3*NWL);
        src = wo + (i - 3*NWL);
    }
    const float4 v = *(const float4*)src;
    f16 o[4];
    o[0] = (f16)v.x; o[1] = (f16)v.y; o[2] = (f16)v.z; o[3] = (f16)v.w;
    *(ushort4*)dst = *(const ushort4*)o;
}

// ---------------------------------------------------------------------------
// MoE conv: mean over E of conv1d(x, w_e)+b_e == conv1d(x, mean_e w_e)+mean_e b_e
// ---------------------------------------------------------------------------
template<typename IT>
__global__ __launch_bounds__(256) void conv_moe(
    const IT* __restrict__ xin,      // [4096, 2048]
    const float* __restrict__ cw,    // [E, K] layer slice
    const float* __restrict__ cb,    // [E]
    f16* __restrict__ xo)            // [4096, 2048] f16
{
    __shared__ float srow[WD];
    __shared__ float swb[KSZ];
    __shared__ float sbb;
    const int tid = threadIdx.x;
    const size_t row = blockIdx.x;
    if (tid < KSZ) {
        float s = 0.f;
        for (int e = 0; e < ED; ++e) s += cw[e*KSZ + tid];
        swb[tid] = s * (1.f/ED);
    }
    if (tid == 32) {
        float s = 0.f;
        for (int e = 0; e < ED; ++e) s += cb[e];
        sbb = s * (1.f/ED);
    }
    const IT* xr = xin + row*WD;
    for (int i = tid; i < WD; i += 256) srow[i] = (float)xr[i];
    __syncthreads();
    const float bb = sbb;
    for (int t0 = 0; t0 < WD; t0 += 256) {
        const int t = t0 + tid;
        float acc = bb;
        #pragma unroll
        for (int k = 0; k < KSZ; ++k) {
            const int idx = t + k - (KSZ/2);
            const float xv = (idx >= 0 && idx < WD) ? srow[idx] : 0.f;
            acc = fmaf(xv, swb[k], acc);
        }
        xo[row*WD + t] = (f16)acc;
    }
}

// ---------------------------------------------------------------------------
// f16 MFMA GEMM, B^T layout, 128x128 tile (verified m97-class structure).
// Kept for the out-projection GEMM (M=4096, K=1024, N=2048 -> 512 blocks).
// ---------------------------------------------------------------------------
template<typename OT>
__global__ __launch_bounds__(256, 2) void gemm_f16(
    const f16* __restrict__ A,   // [M, K]
    const f16* __restrict__ B,   // [N, K]
    const float* __restrict__ c0, const float* __restrict__ c1, const float* __restrict__ c2,
    OT* __restrict__ out,        // [M, N]
    const int K, const int N)
{
    __shared__ f16 sA[128*64];
    __shared__ f16 sB[128*64];
    const int tid  = threadIdx.x;
    const int m0   = blockIdx.x * 128;
    const int n0   = blockIdx.y * 128;
    const int lane = tid & 63;
    const int wave = tid >> 6;
    const int wm   = (wave >> 1) * 64;
    const int wn   = (wave & 1) * 64;
    const int quad = lane >> 4;
    const int r16  = lane & 15;

    f32x4 acc[4][4] = {};

    int arow[4], aoff[4];
    #pragma unroll
    for (int t = 0; t < 4; ++t) {
        const int s = tid + 256*t;
        const int row = s >> 3;
        const int sc8 = ((s & 7) ^ (row & 7)) * 8;
        arow[t] = row;
        aoff[t] = row * K + sc8;
    }

    int aBase[4], aXor[4], bBase[4], bXor[4];
    #pragma unroll
    for (int i = 0; i < 4; ++i) {
        const int ra = wm + i*16 + r16;
        aBase[i] = ra << 3; aXor[i] = ra & 7;
        const int rb = wn + i*16 + r16;
        bBase[i] = rb << 3; bXor[i] = rb & 7;
    }

    const size_t mK = (size_t)m0 * K;
    const size_t nK = (size_t)n0 * K;

    for (int kb = 0; kb < K; kb += 64) {
        #pragma unroll
        for (int t = 0; t < 4; ++t) {
            const int s = tid + 256*t;
            __builtin_amdgcn_global_load_lds(
                (const __attribute__((address_space(1))) unsigned int*)(A + mK + aoff[t] + kb),
                (__attribute__((address_space(3))) unsigned int*)&sA[s*8], 16, 0, 0);
            __builtin_amdgcn_global_load_lds(
                (const __attribute__((address_space(1))) unsigned int*)(B + nK + aoff[t] + kb),
                (__attribute__((address_space(3))) unsigned int*)&sB[s*8], 16, 0, 0);
        }
        __syncthreads();

        #pragma unroll
        for (int ks = 0; ks < 2; ++ks) {
            const int c = ks*4 + quad;
            f16x8 af[4], bfm[4];
            #pragma unroll
            for (int i = 0; i < 4; ++i)
                af[i] = *(const f16x8*)&sA[(aBase[i] | (c ^ aXor[i])) * 8];
            #pragma unroll
            for (int j = 0; j < 4; ++j)
                bfm[j] = *(const f16x8*)&sB[(bBase[j] | (c ^ bXor[j])) * 8];
            #pragma unroll
            for (int i = 0; i < 4; ++i)
                #pragma unroll
                for (int j = 0; j < 4; ++j)
                    acc[i][j] = __builtin_amdgcn_mfma_f32_16x16x32_f16(af[i], bfm[j], acc[i][j], 0, 0, 0);
        }
        __syncthreads();
    }

    #pragma unroll
    for (int j = 0; j < 4; ++j) {
        const int col = n0 + wn + j*16 + r16;
        const float bv = (col < 1024) ? c0[col] : (col < 2048) ? c1[col-1024] : c2[col-2048];
        #pragma unroll
        for (int i = 0; i < 4; ++i) {
            #pragma unroll
            for (int r = 0; r < 4; ++r) {
                const int rowg = m0 + wm + i*16 + quad*4 + r;
                out[(size_t)rowg*N + col] = (OT)(acc[i][j][r] + bv);
            }
        }
    }
}

// ---------------------------------------------------------------------------
// 256x256 8-phase pipelined f16 GEMM (T2+T3+T4+T5), B^T layout, BK=64.
// 512 threads = 8 waves (2M x 4N), per-wave output 128x64.
// LDS 128 KiB: sA/sB x 2 dbuf x 2 halves of [128 x 64] f16, XOR-chunk swizzled
// (slot s holds global 16B-chunk (s&7)^(row&7) of row s>>3 -> bank-uniform
// ds_read_b128 while keeping global_load_lds's linear-destination rule).
//
// Piece schedule per iteration (tiles T0=2it in buf0, T1=2it+1 in buf1);
// one 16 KiB piece (2 x global_load_lds x 512 thr) staged per phase:
//   P1: A-h0(buf1)<-T1   P2: A-h1(buf1)<-T1   P3: B-h0(buf0)<-T0+2
//   P4: B-h1(buf0)<-T0+2 P5: A-h0(buf0)<-T0+2 P6: A-h1(buf0)<-T0+2
//   P7: B-h0(buf1)<-T1+2 P8: B-h1(buf1)<-T1+2
// Counted waits ONLY at P4/P8 end: vmcnt(4) leaves the newest 2 pieces in
// flight and guarantees everything the next 4 phases read has landed.
// Region-reuse safety: a region staged at phase p was last read at a phase q<p
// whose readers drained at their lgkmcnt(0) before barrier(q) < issue(p).
// ---------------------------------------------------------------------------
__global__ __launch_bounds__(512, 2) void gemm256(
    const f16* __restrict__ A,   // [M, K]
    const f16* __restrict__ B,   // [N, K]
    const float* __restrict__ c0, const float* __restrict__ c1, const float* __restrict__ c2,
    f16* __restrict__ out,       // [M, N]
    const int K, const int N)
{
    __shared__ __align__(16) f16 sA[2][2][128*64];
    __shared__ __align__(16) f16 sB[2][2][128*64];

    const int tid  = threadIdx.x;
    const int lane = tid & 63;
    const int wave = tid >> 6;
    const int wr   = wave >> 2;          // 0..1 : A half / 128-row block
    const int wc   = wave & 3;           // 0..3 : 64-col block
    const int quad = lane >> 4;
    const int r16  = lane & 15;
    const int xr   = r16 & 7;            // read-side XOR key (row & 7 == r16 & 7)
    const int bHalf = wc >> 1;
    const int bRowB = (wc & 1) * 64;

    // XCD-bijective block swizzle (nwg % 8 == 0 for both our grids)
    const int nwg  = gridDim.x;
    const int orig = blockIdx.x;
    const int wgid = (orig & 7) * (nwg >> 3) + (orig >> 3);
    const int m0   = (wgid & 15) * 256;     // M = 4096 -> 16 M-tiles
    const int n0   = (wgid >> 4) * 256;

    f32x4 acc[8][4] = {};
    f16x8 bf[4][2];

    // staging: 2 slots/thread per 16 KiB piece; slot s -> row s>>3, chunk (s&7)^(row&7)
    int soff[2];
    #pragma unroll
    for (int t = 0; t < 2; ++t) {
        const int s = tid + 512*t;
        const int row = s >> 3;
        soff[t] = row * K + (((s & 7) ^ (row & 7)) * 8);
    }

    const f16* Abase[2] = { A + (size_t)m0 * K, A + (size_t)(m0 + 128) * K };
    const f16* Bbase[2] = { B + (size_t)n0 * K, B + (size_t)(n0 + 128) * K };

    #define STAGE(DST, BUF, HALF, GBASE)                                          \
      { _Pragma("unroll") for (int t = 0; t < 2; ++t) {                           \
          __builtin_amdgcn_global_load_lds(                                       \
            (const __attribute__((address_space(1))) unsigned int*)((GBASE) + soff[t]), \
            (__attribute__((address_space(3))) unsigned int*)&DST[BUF][HALF][(tid + 512*t)*8], \
            16, 0, 0); } }

    #define LDFRAG(MAT, BUF, HALF, ROW, C) \
      (*(const f16x8*)&MAT[BUF][HALF][ (((ROW)*8) + ((C) ^ xr)) * 8 ])

    #define WAIT_NONE
    #define WAIT_P4  if (!klast) { asm volatile("s_waitcnt vmcnt(4)" ::: "memory"); } \
                     else        { asm volatile("s_waitcnt vmcnt(0)" ::: "memory"); }
    #define WAIT_P8  if (!klast) { asm volatile("s_waitcnt vmcnt(4)" ::: "memory"); }

    // Phase: ds-read this quadrant's frags, issue one stage piece, barrier,
    // drain LDS reads, MFMA cluster under setprio, counted wait, barrier.
    #define PHASE(BUF, Q, WAIT, ...)                                              \
    {                                                                             \
      if ((Q) == 0) {                                                             \
        _Pragma("unroll") for (int j = 0; j < 4; ++j) {                           \
          bf[j][0] = LDFRAG(sB, BUF, bHalf, bRowB + j*16 + r16, quad);            \
          bf[j][1] = LDFRAG(sB, BUF, bHalf, bRowB + j*16 + r16, 4 + quad);        \
        }                                                                         \
      }                                                                           \
      f16x8 a00 = LDFRAG(sA, BUF, wr, (2*(Q))*16   + r16, quad);                  \
      f16x8 a01 = LDFRAG(sA, BUF, wr, (2*(Q))*16   + r16, 4 + quad);              \
      f16x8 a10 = LDFRAG(sA, BUF, wr, (2*(Q)+1)*16 + r16, quad);                  \
      f16x8 a11 = LDFRAG(sA, BUF, wr, (2*(Q)+1)*16 + r16, 4 + quad);              \
      __VA_ARGS__;                                                                \
      __builtin_amdgcn_s_barrier();                                               \
      asm volatile("s_waitcnt lgkmcnt(0)" ::: "memory");                          \
      __builtin_amdgcn_sched_barrier(0);                                          \
      __builtin_amdgcn_s_setprio(1);                                              \
      _Pragma("unroll") for (int j = 0; j < 4; ++j) {                             \
        acc[2*(Q)][j]   = __builtin_amdgcn_mfma_f32_16x16x32_f16(a00, bf[j][0], acc[2*(Q)][j],   0,0,0); \
        acc[2*(Q)+1][j] = __builtin_amdgcn_mfma_f32_16x16x32_f16(a10, bf[j][0], acc[2*(Q)+1][j], 0,0,0); \
      }                                                                           \
      _Pragma("unroll") for (int j = 0; j < 4; ++j) {                             \
        acc[2*(Q)][j]   = __builtin_amdgcn_mfma_f32_16x16x32_f16(a01, bf[j][1], acc[2*(Q)][j],   0,0,0); \
        acc[2*(Q)+1][j] = __builtin_amdgcn_mfma_f32_16x16x32_f16(a11, bf[j][1], acc[2*(Q)+1][j], 0,0,0); \
      }                                                                           \
      __builtin_amdgcn_s_setprio(0);                                              \
      WAIT;                                                                       \
      __builtin_amdgcn_s_barrier();                                               \
    }

    // prologue: tile0 fully (4 pieces), tile1 B-halves (2 pieces, left in flight)
    STAGE(sB, 0, 0, Bbase[0]);
    STAGE(sB, 0, 1, Bbase[1]);
    STAGE(sA, 0, 0, Abase[0]);
    STAGE(sA, 0, 1, Abase[1]);
    STAGE(sB, 1, 0, Bbase[0] + 64);
    STAGE(sB, 1, 1, Bbase[1] + 64);
    asm volatile("s_waitcnt vmcnt(4)" ::: "memory");
    __builtin_amdgcn_s_barrier();

    const int NIT = K >> 7;   // K / 128, two K-tiles (BK=64) per iteration
    for (int it = 0; it < NIT; ++it) {
        const bool klast = (it == NIT - 1);
        const int kb1 = (2*it + 1) * 64;
        const int kb2 = kb1 + 64;
        const int kb3 = kb1 + 128;
        // ---- K-tile 2it from buf0 ----
        PHASE(0, 0, WAIT_NONE, STAGE(sA, 1, 0, Abase[0] + kb1))
        PHASE(0, 1, WAIT_NONE, STAGE(sA, 1, 1, Abase[1] + kb1))
        PHASE(0, 2, WAIT_NONE, if (!klast) STAGE(sB, 0, 0, Bbase[0] + kb2))
        PHASE(0, 3, WAIT_P4,   if (!klast) STAGE(sB, 0, 1, Bbase[1] + kb2))
        // ---- K-tile 2it+1 from buf1 ----
        PHASE(1, 0, WAIT_NONE, if (!klast) STAGE(sA, 0, 0, Abase[0] + kb2))
        PHASE(1, 1, WAIT_NONE, if (!klast) STAGE(sA, 0, 1, Abase[1] + kb2))
        PHASE(1, 2, WAIT_NONE, if (!klast) STAGE(sB, 1, 0, Bbase[0] + kb3))
        PHASE(1, 3, WAIT_P8,   if (!klast) STAGE(sB, 1, 1, Bbase[1] + kb3))
    }

    // epilogue: C/D mapping (16x16x32): col = lane&15, row = quad*4 + r
    #pragma unroll
    for (int j = 0; j < 4; ++j) {
        const int col = n0 + wc*64 + j*16 + r16;
        const float bv = (col < 1024) ? c0[col] : (col < 2048) ? c1[col-1024] : c2[col-2048];
        #pragma unroll
        for (int mi = 0; mi < 8; ++mi) {
            #pragma unroll
            for (int r = 0; r < 4; ++r) {
                const int rowg = m0 + wr*128 + mi*16 + quad*4 + r;
                out[(size_t)rowg*N + col] = (f16)(acc[mi][j][r] + bv);
            }
        }
    }

    #undef STAGE
    #undef LDFRAG
    #undef WAIT_NONE
    #undef WAIT_P4
    #undef WAIT_P8
    #undef PHASE
}

// ---------------------------------------------------------------------------
// Stockham radix-4 DIF FFT, 1024 points, 256 threads, interleaved f32x2 in LDS
// ---------------------------------------------------------------------------
__device__ inline void fft1024r4(f32x2* x, f32x2* y, const int tid)
{
    f32x2* src = x;
    f32x2* dst = y;
    #pragma unroll
    for (int st = 0; st < 5; ++st) {
        const int ls = 2*st;
        const int s  = 1 << ls;
        const int p  = tid >> ls;
        const int q  = tid & (s - 1);
        const float invn = 1.f / (float)(1024 >> ls);
        const f32x2 a = src[PAD(tid)];
        const f32x2 b = src[PAD(tid + 256)];
        const f32x2 c = src[PAD(tid + 512)];
        const f32x2 d = src[PAD(tid + 768)];
        float ws, wc;
        __sincosf(-2.f*PI_F * (float)p * invn, &ws, &wc);
        const float apcx = a.x + c.x, apcy = a.y + c.y;
        const float amcx = a.x - c.x, amcy = a.y - c.y;
        const float bpdx = b.x + d.x, bpdy = b.y + d.y;
        const float bmdx = b.x - d.x, bmdy = b.y - d.y;
        f32x2 y0; y0.x = apcx + bpdx; y0.y = apcy + bpdy;
        const float t1x = amcx + bmdy, t1y = amcy - bmdx;   // amc - i*bmd
        const float t2x = apcx - bpdx, t2y = apcy - bpdy;
        const float t3x = amcx - bmdy, t3y = amcy + bmdx;   // amc + i*bmd
        const float w2x = wc*wc - ws*ws, w2y = 2.f*wc*ws;
        const float w3x = w2x*wc - w2y*ws, w3y = w2x*ws + w2y*wc;
        f32x2 y1; y1.x = wc*t1x - ws*t1y;   y1.y = wc*t1y + ws*t1x;
        f32x2 y2; y2.x = w2x*t2x - w2y*t2y; y2.y = w2x*t2y + w2y*t2x;
        f32x2 y3; y3.x = w3x*t3x - w3y*t3y; y3.y = w3x*t3y + w3y*t3x;
        const int base = q + ((p * s) << 2);
        dst[PAD(base)]       = y0;
        dst[PAD(base + s)]   = y1;
        dst[PAD(base + 2*s)] = y2;
        dst[PAD(base + 3*s)] = y3;
        __syncthreads();
        f32x2* t = src; src = dst; dst = t;
    }
}

// ---------------------------------------------------------------------------
// FFT-domain attention, two rows per block, packed-real FFTs (f16 in, f16 out)
// ---------------------------------------------------------------------------
__global__ __launch_bounds__(256) void fft_attn2(
    const f16* __restrict__ qkv, f16* __restrict__ outg)
{
    __shared__ f32x2 X[PAD(1023)+1], Y[PAD(1023)+1];
    const int tid = threadIdx.x;
    const size_t row0 = (size_t)blockIdx.x * 2;
    const f16* r1 = qkv + row0*QKVN;        // q1 | k1 | v1
    const f16* r2 = r1 + QKVN;              // q2 | k2 | v2

    f32x2 V1[4], V2[4], S1[4], S2[4];

    // ---- FFT(v1 + i*v2) -> V1, V2 in registers ----
    #pragma unroll
    for (int k = 0; k < 4; ++k) {
        const int i = tid + 256*k;
        f32x2 t; t.x = (float)r1[2048+i]; t.y = (float)r2[2048+i];
        X[PAD(i)] = t;
    }
    __syncthreads();
    fft1024r4(X, Y, tid);
    #pragma unroll
    for (int k = 0; k < 4; ++k) {
        const int f = tid + 256*k;
        const int g = (PD - f) & (PD-1);
        const f32x2 z1 = Y[PAD(f)], z2 = Y[PAD(g)];
        V1[k].x = 0.5f*(z1.x + z2.x); V1[k].y = 0.5f*(z1.y - z2.y);
        V2[k].x = 0.5f*(z1.y + z2.y); V2[k].y = 0.5f*(z2.x - z1.x);
    }

    // ---- FFT(q1 + i*k1) ; S1 = conj(K1*conj(Q1)*V1/32) ----
    #pragma unroll
    for (int k = 0; k < 4; ++k) {
        const int i = tid + 256*k;
        f32x2 t; t.x = (float)r1[i]; t.y = (float)r1[1024+i];
        X[PAD(i)] = t;
    }
    __syncthreads();   // fences the V-split reads of Y above
    fft1024r4(X, Y, tid);
    #pragma unroll
    for (int k = 0; k < 4; ++k) {
        const int f = tid + 256*k;
        const int g = (PD - f) & (PD-1);
        const f32x2 z1 = Y[PAD(f)], z2 = Y[PAD(g)];
        const float Qr = 0.5f*(z1.x + z2.x), Qi = 0.5f*(z1.y - z2.y);
        const float Kr = 0.5f*(z1.y + z2.y), Ki = 0.5f*(z2.x - z1.x);
        const float Pr = (Kr*Qr + Ki*Qi) * (1.f/32.f);
        const float Pi = (Ki*Qr - Kr*Qi) * (1.f/32.f);
        S1[k].x = Pr*V1[k].x - Pi*V1[k].y;
        S1[k].y = -(Pr*V1[k].y + Pi*V1[k].x);
    }

    // ---- FFT(q2 + i*k2) ; S2 = conj(K2*conj(Q2)*V2/32) ----
    #pragma unroll
    for (int k = 0; k < 4; ++k) {
        const int i = tid + 256*k;
        f32x2 t; t.x = (float)r2[i]; t.y = (float)r2[1024+i];
        X[PAD(i)] = t;
    }
    __syncthreads();
    fft1024r4(X, Y, tid);
    #pragma unroll
    for (int k = 0; k < 4; ++k) {
        const int f = tid + 256*k;
        const int g = (PD - f) & (PD-1);
        const f32x2 z1 = Y[PAD(f)], z2 = Y[PAD(g)];
        const float Qr = 0.5f*(z1.x + z2.x), Qi = 0.5f*(z1.y - z2.y);
        const float Kr = 0.5f*(z1.y + z2.y), Ki = 0.5f*(z2.x - z1.x);
        const float Pr = (Kr*Qr + Ki*Qi) * (1.f/32.f);
        const float Pi = (Ki*Qr - Kr*Qi) * (1.f/32.f);
        S2[k].x = Pr*V2[k].x - Pi*V2[k].y;
        S2[k].y = -(Pr*V2[k].y + Pi*V2[k].x);
    }

    // ---- packed inverse: FFT(S1 + i*S2) ----
    #pragma unroll
    for (int k = 0; k < 4; ++k) {
        const int f = tid + 256*k;
        f32x2 t; t.x = S1[k].x - S2[k].y; t.y = S1[k].y + S2[k].x;
        X[PAD(f)] = t;
    }
    __syncthreads();
    fft1024r4(X, Y, tid);
    f16* o1 = outg + row0*PD;
    f16* o2 = o1 + PD;
    #pragma unroll
    for (int k = 0; k < 4; ++k) {
        const int n = tid + 256*k;
        const f32x2 z = Y[PAD(n)];
        o1[n] = (f16)(z.x * (1.f/1024.f));
        o2[n] = (f16)(z.y * (1.f/1024.f));
    }
}

// ---------------------------------------------------------------------------
extern "C" void kernel_launch(void* const* d_in, const int* in_sizes, int n_in,
                              void* d_out, int out_size, void* d_ws, size_t ws_size,
                              hipStream_t stream)
{
    const float* x      = (const float*)d_in[0];
    const float* conv_w = (const float*)d_in[1];   // [L,E,1,K]
    const float* conv_b = (const float*)d_in[2];   // [L,E]
    const float* wq     = (const float*)d_in[3];   // [L,P,W]
    const float* bq     = (const float*)d_in[4];   // [L,P]
    const float* wk     = (const float*)d_in[5];
    const float* bk     = (const float*)d_in[6];
    const float* wv     = (const float*)d_in[7];
    const float* bv     = (const float*)d_in[8];
    const float* wo     = (const float*)d_in[9];   // [L,W,P]
    const float* bo     = (const float*)d_in[10];  // [L,W]

    // workspace layout (64 MiB), per-layer weight slots reused:
    //   0M..12M : wqkv16 f16 [3072, 2048]  (q rows 0-1023, k 1024-2047, v 2048-3071)
    //  12M..16M : wo16   f16 [2048, 1024]
    //  16M..40M : qkvbuf f16 [4096, 3072]  (row-interleaved q|k|v)
    //  40M..56M : xc16   f16 [4096, 2048]  (first 8 MiB also aliased wvr16 [4096,1024])
    //  56M..72M : xmid   f16 [4096, 2048]
    char* ws = (char*)d_ws;
    const size_t MB = 1024*1024;
    f16*   wqkv16 = (f16*)(ws);
    f16*   wo16   = (f16*)(ws + 12*MB);
    f16*   qkvbuf = (f16*)(ws + 16*MB);
    f16*   xc16   = (f16*)(ws + 40*MB);
    f16*   xmid   = (f16*)(ws + 56*MB);
    f16*   wvr16  = xc16;   // alias: xc dead once the QKV GEMM completes

    for (int l = 0; l < LN; ++l) {
        // convert this layer's 4 weight tensors in one dispatch
        cvt_layer<<<dim3(4*NWL/4/256), dim3(256), 0, stream>>>(
            wq + (size_t)l*NWL, wk + (size_t)l*NWL, wv + (size_t)l*NWL, wo + (size_t)l*NWL,
            wqkv16, wo16);

        if (l == 0)
            conv_moe<float><<<dim3(MROWS), dim3(256), 0, stream>>>(
                x, conv_w, conv_b, xc16);
        else
            conv_moe<f16><<<dim3(MROWS), dim3(256), 0, stream>>>(
                xmid, conv_w + (size_t)l*ED*KSZ, conv_b + (size_t)l*ED, xc16);

        // qkv = xc @ wqkv^T + [bq|bk|bv]   (M=4096, K=2048, N=3072), f16 out
        // 256x256 8-phase pipelined GEMM: grid 16x12 = 192 blocks (192%8==0)
        gemm256<<<dim3((MROWS/256)*(QKVN/256)), dim3(512), 0, stream>>>(
            xc16, wqkv16,
            bq + (size_t)l*PD, bk + (size_t)l*PD, bv + (size_t)l*PD,
            qkvbuf, WD, QKVN);

        fft_attn2<<<dim3(MROWS/2), dim3(256), 0, stream>>>(qkvbuf, wvr16);

        // xnext = wvr @ wo^T + bo  (M=4096, K=1024, N=2048)
        if (l == LN-1)
            gemm_f16<float><<<dim3(MROWS/128, WD/128), dim3(256), 0, stream>>>(
                wvr16, wo16,
                bo + (size_t)l*WD, bo + (size_t)l*WD + PD, bo + (size_t)l*WD + PD,
                (float*)d_out, PD, WD);
        else
            gemm_f16<f16><<<dim3(MROWS/128, WD/128), dim3(256), 0, stream>>>(
                wvr16, wo16,
                bo + (size_t)l*WD, bo + (size_t)l*WD + PD, bo + (size_t)l*WD + PD,
                xmid, PD, WD);
    }
}

// Round 2
// 405.149 us; speedup vs baseline: 1.0330x; 1.0330x over previous
//
#include <hip/hip_runtime.h>
#include <hip/hip_bf16.h>

// Problem constants (FEDformerEncoder): BS=32 CNT=128 W=2048 P=1024 E=8 K=25 L=2
#define BSZ 32
#define CNTS 128
#define WD 2048
#define PD 1024
#define ED 8
#define KSZ 25
#define LN 2
#define MROWS (BSZ*CNTS)   // 4096
#define QKVN (3*PD)        // 3072
#define NWL (PD*WD)        // 2M elements per weight tensor per layer

typedef _Float16 f16;
typedef __attribute__((ext_vector_type(8))) _Float16 f16x8;  // 8 f16 = 4 VGPRs
typedef __attribute__((ext_vector_type(4))) float f32x4;
typedef __attribute__((ext_vector_type(2))) float f32x2;

#define PI_F 3.14159265358979323846f
// LDS physical index padding for the FFT (+1 float2 per 32 elements)
#define PAD(a) ((a) + ((a) >> 5))

// ---------------------------------------------------------------------------
// Per-layer weight conversion, one dispatch: wq|wk|wv -> wqkv16 packed, wo -> wo16.
// ---------------------------------------------------------------------------
__global__ __launch_bounds__(256) void cvt_layer(
    const float* __restrict__ wq, const float* __restrict__ wk,
    const float* __restrict__ wv, const float* __restrict__ wo,
    f16* __restrict__ wqkv16, f16* __restrict__ wo16)
{
    const int i = (blockIdx.x * 256 + threadIdx.x) * 4;
    const float* src;
    f16* dst;
    if (i < 3*NWL) {
        dst = wqkv16 + i;
        src = (i < NWL) ? wq + i : (i < 2*NWL) ? wk + (i - NWL) : wv + (i - 2*NWL);
    } else {
        dst = wo16 + (i - 3*NWL);
        src = wo + (i - 3*NWL);
    }
    const float4 v = *(const float4*)src;
    f16 o[4];
    o[0] = (f16)v.x; o[1] = (f16)v.y; o[2] = (f16)v.z; o[3] = (f16)v.w;
    *(ushort4*)dst = *(const ushort4*)o;
}

// ---------------------------------------------------------------------------
// MoE conv: mean over E of conv1d(x, w_e)+b_e == conv1d(x, mean_e w_e)+mean_e b_e
// ---------------------------------------------------------------------------
template<typename IT>
__global__ __launch_bounds__(256) void conv_moe(
    const IT* __restrict__ xin,      // [4096, 2048]
    const float* __restrict__ cw,    // [E, K] layer slice
    const float* __restrict__ cb,    // [E]
    f16* __restrict__ xo)            // [4096, 2048] f16
{
    __shared__ float srow[WD];
    __shared__ float swb[KSZ];
    __shared__ float sbb;
    const int tid = threadIdx.x;
    const size_t row = blockIdx.x;
    if (tid < KSZ) {
        float s = 0.f;
        for (int e = 0; e < ED; ++e) s += cw[e*KSZ + tid];
        swb[tid] = s * (1.f/ED);
    }
    if (tid == 32) {
        float s = 0.f;
        for (int e = 0; e < ED; ++e) s += cb[e];
        sbb = s * (1.f/ED);
    }
    const IT* xr = xin + row*WD;
    for (int i = tid; i < WD; i += 256) srow[i] = (float)xr[i];
    __syncthreads();
    const float bb = sbb;
    for (int t0 = 0; t0 < WD; t0 += 256) {
        const int t = t0 + tid;
        float acc = bb;
        #pragma unroll
        for (int k = 0; k < KSZ; ++k) {
            const int idx = t + k - (KSZ/2);
            const float xv = (idx >= 0 && idx < WD) ? srow[idx] : 0.f;
            acc = fmaf(xv, swb[k], acc);
        }
        xo[row*WD + t] = (f16)acc;
    }
}

// ---------------------------------------------------------------------------
// f16 MFMA GEMM, B^T layout, 128x128 tile (verified m97-class structure).
// Kept for the out-projection GEMM (M=4096, K=1024, N=2048 -> 512 blocks).
// ---------------------------------------------------------------------------
template<typename OT>
__global__ __launch_bounds__(256, 2) void gemm_f16(
    const f16* __restrict__ A,   // [M, K]
    const f16* __restrict__ B,   // [N, K]
    const float* __restrict__ c0, const float* __restrict__ c1, const float* __restrict__ c2,
    OT* __restrict__ out,        // [M, N]
    const int K, const int N)
{
    __shared__ f16 sA[128*64];
    __shared__ f16 sB[128*64];
    const int tid  = threadIdx.x;
    const int m0   = blockIdx.x * 128;
    const int n0   = blockIdx.y * 128;
    const int lane = tid & 63;
    const int wave = tid >> 6;
    const int wm   = (wave >> 1) * 64;
    const int wn   = (wave & 1) * 64;
    const int quad = lane >> 4;
    const int r16  = lane & 15;

    f32x4 acc[4][4] = {};

    int aoff[4];
    #pragma unroll
    for (int t = 0; t < 4; ++t) {
        const int s = tid + 256*t;
        const int row = s >> 3;
        const int sc8 = ((s & 7) ^ (row & 7)) * 8;
        aoff[t] = row * K + sc8;
    }

    int aBase[4], aXor[4], bBase[4], bXor[4];
    #pragma unroll
    for (int i = 0; i < 4; ++i) {
        const int ra = wm + i*16 + r16;
        aBase[i] = ra << 3; aXor[i] = ra & 7;
        const int rb = wn + i*16 + r16;
        bBase[i] = rb << 3; bXor[i] = rb & 7;
    }

    const size_t mK = (size_t)m0 * K;
    const size_t nK = (size_t)n0 * K;

    for (int kb = 0; kb < K; kb += 64) {
        #pragma unroll
        for (int t = 0; t < 4; ++t) {
            const int s = tid + 256*t;
            __builtin_amdgcn_global_load_lds(
                (const __attribute__((address_space(1))) unsigned int*)(A + mK + aoff[t] + kb),
                (__attribute__((address_space(3))) unsigned int*)&sA[s*8], 16, 0, 0);
            __builtin_amdgcn_global_load_lds(
                (const __attribute__((address_space(1))) unsigned int*)(B + nK + aoff[t] + kb),
                (__attribute__((address_space(3))) unsigned int*)&sB[s*8], 16, 0, 0);
        }
        __syncthreads();

        #pragma unroll
        for (int ks = 0; ks < 2; ++ks) {
            const int c = ks*4 + quad;
            f16x8 af[4], bfm[4];
            #pragma unroll
            for (int i = 0; i < 4; ++i)
                af[i] = *(const f16x8*)&sA[(aBase[i] | (c ^ aXor[i])) * 8];
            #pragma unroll
            for (int j = 0; j < 4; ++j)
                bfm[j] = *(const f16x8*)&sB[(bBase[j] | (c ^ bXor[j])) * 8];
            #pragma unroll
            for (int i = 0; i < 4; ++i)
                #pragma unroll
                for (int j = 0; j < 4; ++j)
                    acc[i][j] = __builtin_amdgcn_mfma_f32_16x16x32_f16(af[i], bfm[j], acc[i][j], 0, 0, 0);
        }
        __syncthreads();
    }

    #pragma unroll
    for (int j = 0; j < 4; ++j) {
        const int col = n0 + wn + j*16 + r16;
        const float bv = (col < 1024) ? c0[col] : (col < 2048) ? c1[col-1024] : c2[col-2048];
        #pragma unroll
        for (int i = 0; i < 4; ++i) {
            #pragma unroll
            for (int r = 0; r < 4; ++r) {
                const int rowg = m0 + wm + i*16 + quad*4 + r;
                out[(size_t)rowg*N + col] = (OT)(acc[i][j][r] + bv);
            }
        }
    }
}

// ---------------------------------------------------------------------------
// 256x256 pipelined f16 GEMM, B^T layout, BK=64, 512 thr = 8 waves (2M x 4N).
// 4-barrier-per-iteration schedule (vs 16 in the lockstep version): barriers
// only where the hazard graph requires them:
//   B1: after Q0(buf0)  -- retires B-buf0 readers before B-buf0 restage (P3/P4)
//   B2: buffer switch   -- collective vmcnt(4) publishes A-buf1 + B-buf1
//   B3: after Q0(buf1)  -- retires B-buf1 readers before B-buf1 restage (P7/P8)
//   B4: iteration end   -- collective vmcnt(4) publishes A-buf0 + B-buf0
// Within Q1..Q3 windows, A-frag ds_reads issue under the previous quadrant's
// MFMA with counted lgkmcnt(4) -> LDS reads overlap the matrix pipe.
// Stage order per iteration (1 piece = 16 KiB = 2 global_load_lds / thread):
//   P1:A1h0 P2:A1h1 P3:B0'h0 P4:B0'h1 | P5:A0'h0 P6:A0'h1 P7:B1'h0 P8:B1'h1
// vmcnt(4) at B2/B4 leaves the 2 newest pieces in flight (never drains to 0
// in the main loop).  XOR-chunk LDS swizzle (slot s holds chunk (s&7)^(row&7))
// keeps ds_read_b128 bank-conflict-free under global_load_lds's linear rule.
// 2D XCD chunking: XCD x (= blockIdx%8) owns a 4m x 6n tile chunk (10 MB
// working set vs 18 MB with m-fast-varying), for the 16x12-tile QKV grid.
// ---------------------------------------------------------------------------
__global__ __launch_bounds__(512, 2) void gemm256(
    const f16* __restrict__ A,   // [M, K]
    const f16* __restrict__ B,   // [N, K]
    const float* __restrict__ c0, const float* __restrict__ c1, const float* __restrict__ c2,
    f16* __restrict__ out,       // [M, N]
    const int K, const int N)
{
    __shared__ __align__(16) f16 sA[2][2][128*64];
    __shared__ __align__(16) f16 sB[2][2][128*64];

    const int tid  = threadIdx.x;
    const int lane = tid & 63;
    const int wave = tid >> 6;
    const int wr   = wave >> 2;          // 0..1 : A 128-row block
    const int wc   = wave & 3;           // 0..3 : 64-col block
    const int quad = lane >> 4;
    const int r16  = lane & 15;
    const int xr   = r16 & 7;            // read-side XOR key
    const int bHalf = wc >> 1;
    const int bRowB = (wc & 1) * 64;

    // 2D XCD chunking (grid = 16 m-tiles x 12 n-tiles = 192 blocks):
    // XCD x = orig%8 -> chunk (x>>1, x&1) of 4m x 6n tiles.
    const int orig = blockIdx.x;
    const int xcd  = orig & 7;
    const int loc  = orig >> 3;          // 0..23
    const int mt   = (xcd >> 1) * 4 + (loc & 3);
    const int nt   = (xcd & 1) * 6 + (loc >> 2);
    const int m0   = mt * 256;
    const int n0   = nt * 256;

    f32x4 acc[8][4] = {};
    f16x8 bf[4][2];
    f16x8 aX0, aX1, aX2, aX3, aY0, aY1, aY2, aY3, aZ0, aZ1, aZ2, aZ3;

    // staging: 2 slots/thread per 16 KiB piece; slot s -> row s>>3, chunk (s&7)^(row&7)
    int soff[2];
    #pragma unroll
    for (int t = 0; t < 2; ++t) {
        const int s = tid + 512*t;
        const int row = s >> 3;
        soff[t] = row * K + (((s & 7) ^ (row & 7)) * 8);
    }

    const f16* Abase[2] = { A + (size_t)m0 * K, A + (size_t)(m0 + 128) * K };
    const f16* Bbase[2] = { B + (size_t)n0 * K, B + (size_t)(n0 + 128) * K };

    #define STAGE(DST, BUF, HALF, GBASE)                                          \
      { _Pragma("unroll") for (int t = 0; t < 2; ++t) {                           \
          __builtin_amdgcn_global_load_lds(                                       \
            (const __attribute__((address_space(1))) unsigned int*)((GBASE) + soff[t]), \
            (__attribute__((address_space(3))) unsigned int*)&DST[BUF][HALF][(tid + 512*t)*8], \
            16, 0, 0); } }

    #define LDFRAG(MAT, BUF, HALF, ROW, C) \
      (*(const f16x8*)&MAT[BUF][HALF][ (((ROW)*8) + ((C) ^ xr)) * 8 ])

    #define READ_BF(BUF)                                                          \
      { _Pragma("unroll") for (int j = 0; j < 4; ++j) {                           \
          bf[j][0] = LDFRAG(sB, BUF, bHalf, bRowB + j*16 + r16, quad);            \
          bf[j][1] = LDFRAG(sB, BUF, bHalf, bRowB + j*16 + r16, 4 + quad);        \
        } }

    #define READ_A(BUF, Q, D0, D1, D2, D3)                                        \
      D0 = LDFRAG(sA, BUF, wr, (2*(Q))*16   + r16, quad);                         \
      D1 = LDFRAG(sA, BUF, wr, (2*(Q))*16   + r16, 4 + quad);                     \
      D2 = LDFRAG(sA, BUF, wr, (2*(Q)+1)*16 + r16, quad);                         \
      D3 = LDFRAG(sA, BUF, wr, (2*(Q)+1)*16 + r16, 4 + quad);

    #define MFMA_Q(Q, D0, D1, D2, D3)                                             \
      __builtin_amdgcn_s_setprio(1);                                              \
      { _Pragma("unroll") for (int jj = 0; jj < 4; ++jj) {                        \
          acc[2*(Q)][jj]   = __builtin_amdgcn_mfma_f32_16x16x32_f16(D0, bf[jj][0], acc[2*(Q)][jj],   0,0,0); \
          acc[2*(Q)+1][jj] = __builtin_amdgcn_mfma_f32_16x16x32_f16(D2, bf[jj][0], acc[2*(Q)+1][jj], 0,0,0); \
        } }                                                                       \
      { _Pragma("unroll") for (int jj = 0; jj < 4; ++jj) {                        \
          acc[2*(Q)][jj]   = __builtin_amdgcn_mfma_f32_16x16x32_f16(D1, bf[jj][1], acc[2*(Q)][jj],   0,0,0); \
          acc[2*(Q)+1][jj] = __builtin_amdgcn_mfma_f32_16x16x32_f16(D3, bf[jj][1], acc[2*(Q)+1][jj], 0,0,0); \
        } }                                                                       \
      __builtin_amdgcn_s_setprio(0);

    #define LGKM(n) asm volatile("s_waitcnt lgkmcnt(" #n ")" ::: "memory");       \
                    __builtin_amdgcn_sched_barrier(0);
    #define VMC(n)  asm volatile("s_waitcnt vmcnt(" #n ")" ::: "memory");
    #define BAR()   __builtin_amdgcn_s_barrier();

    // prologue: tile0 fully (4 pieces), tile1 B-halves (2 pieces, left in flight)
    STAGE(sB, 0, 0, Bbase[0]);
    STAGE(sB, 0, 1, Bbase[1]);
    STAGE(sA, 0, 0, Abase[0]);
    STAGE(sA, 0, 1, Abase[1]);
    STAGE(sB, 1, 0, Bbase[0] + 64);
    STAGE(sB, 1, 1, Bbase[1] + 64);
    VMC(4)
    BAR()

    const int NIT = K >> 7;   // two K-tiles (BK=64) per iteration
    for (int it = 0; it < NIT; ++it) {
        const bool kl = (it == NIT - 1);
        const int kb1 = (2*it + 1) * 64;
        const int kb2 = kb1 + 64;
        const int kb3 = kb1 + 128;

        // ---------- K-tile 2it : buf0 ----------
        STAGE(sA, 1, 0, Abase[0] + kb1);                       // P1
        READ_BF(0)
        READ_A(0, 0, aX0, aX1, aX2, aX3)
        LGKM(0)
        MFMA_Q(0, aX0, aX1, aX2, aX3)
        BAR()                                                  // B1
        STAGE(sA, 1, 1, Abase[1] + kb1);                       // P2
        READ_A(0, 1, aY0, aY1, aY2, aY3)
        READ_A(0, 2, aZ0, aZ1, aZ2, aZ3)
        LGKM(4)
        MFMA_Q(1, aY0, aY1, aY2, aY3)
        if (!kl) STAGE(sB, 0, 0, Bbase[0] + kb2);              // P3
        READ_A(0, 3, aX0, aX1, aX2, aX3)
        LGKM(4)
        MFMA_Q(2, aZ0, aZ1, aZ2, aZ3)
        if (!kl) STAGE(sB, 0, 1, Bbase[1] + kb2);              // P4
        LGKM(0)
        MFMA_Q(3, aX0, aX1, aX2, aX3)
        if (!kl) { VMC(4) } else { VMC(0) }
        BAR()                                                  // B2

        // ---------- K-tile 2it+1 : buf1 ----------
        if (!kl) STAGE(sA, 0, 0, Abase[0] + kb2);              // P5
        READ_BF(1)
        READ_A(1, 0, aX0, aX1, aX2, aX3)
        LGKM(0)
        MFMA_Q(0, aX0, aX1, aX2, aX3)
        BAR()                                                  // B3
        if (!kl) STAGE(sA, 0, 1, Abase[1] + kb2);              // P6
        READ_A(1, 1, aY0, aY1, aY2, aY3)
        READ_A(1, 2, aZ0, aZ1, aZ2, aZ3)
        LGKM(4)
        MFMA_Q(1, aY0, aY1, aY2, aY3)
        if (!kl) STAGE(sB, 1, 0, Bbase[0] + kb3);              // P7
        READ_A(1, 3, aX0, aX1, aX2, aX3)
        LGKM(4)
        MFMA_Q(2, aZ0, aZ1, aZ2, aZ3)
        if (!kl) STAGE(sB, 1, 1, Bbase[1] + kb3);              // P8
        LGKM(0)
        MFMA_Q(3, aX0, aX1, aX2, aX3)
        if (!kl) { VMC(4) }
        BAR()                                                  // B4
    }

    // epilogue: C/D mapping (16x16x32): col = lane&15, row = quad*4 + r
    #pragma unroll
    for (int j = 0; j < 4; ++j) {
        const int col = n0 + wc*64 + j*16 + r16;
        const float bv = (col < 1024) ? c0[col] : (col < 2048) ? c1[col-1024] : c2[col-2048];
        #pragma unroll
        for (int mi = 0; mi < 8; ++mi) {
            #pragma unroll
            for (int r = 0; r < 4; ++r) {
                const int rowg = m0 + wr*128 + mi*16 + quad*4 + r;
                out[(size_t)rowg*N + col] = (f16)(acc[mi][j][r] + bv);
            }
        }
    }

    #undef STAGE
    #undef LDFRAG
    #undef READ_BF
    #undef READ_A
    #undef MFMA_Q
    #undef LGKM
    #undef VMC
    #undef BAR
}

// ---------------------------------------------------------------------------
// Stockham radix-4 DIF FFT, 1024 points, 256 threads, interleaved f32x2 in LDS
// ---------------------------------------------------------------------------
__device__ inline void fft1024r4(f32x2* x, f32x2* y, const int tid)
{
    f32x2* src = x;
    f32x2* dst = y;
    #pragma unroll
    for (int st = 0; st < 5; ++st) {
        const int ls = 2*st;
        const int s  = 1 << ls;
        const int p  = tid >> ls;
        const int q  = tid & (s - 1);
        const float invn = 1.f / (float)(1024 >> ls);
        const f32x2 a = src[PAD(tid)];
        const f32x2 b = src[PAD(tid + 256)];
        const f32x2 c = src[PAD(tid + 512)];
        const f32x2 d = src[PAD(tid + 768)];
        float ws, wc;
        __sincosf(-2.f*PI_F * (float)p * invn, &ws, &wc);
        const float apcx = a.x + c.x, apcy = a.y + c.y;
        const float amcx = a.x - c.x, amcy = a.y - c.y;
        const float bpdx = b.x + d.x, bpdy = b.y + d.y;
        const float bmdx = b.x - d.x, bmdy = b.y - d.y;
        f32x2 y0; y0.x = apcx + bpdx; y0.y = apcy + bpdy;
        const float t1x = amcx + bmdy, t1y = amcy - bmdx;   // amc - i*bmd
        const float t2x = apcx - bpdx, t2y = apcy - bpdy;
        const float t3x = amcx - bmdy, t3y = amcy + bmdx;   // amc + i*bmd
        const float w2x = wc*wc - ws*ws, w2y = 2.f*wc*ws;
        const float w3x = w2x*wc - w2y*ws, w3y = w2x*ws + w2y*wc;
        f32x2 y1; y1.x = wc*t1x - ws*t1y;   y1.y = wc*t1y + ws*t1x;
        f32x2 y2; y2.x = w2x*t2x - w2y*t2y; y2.y = w2x*t2y + w2y*t2x;
        f32x2 y3; y3.x = w3x*t3x - w3y*t3y; y3.y = w3x*t3y + w3y*t3x;
        const int base = q + ((p * s) << 2);
        dst[PAD(base)]       = y0;
        dst[PAD(base + s)]   = y1;
        dst[PAD(base + 2*s)] = y2;
        dst[PAD(base + 3*s)] = y3;
        __syncthreads();
        f32x2* t = src; src = dst; dst = t;
    }
}

// ---------------------------------------------------------------------------
// FFT-domain attention, two rows per block, packed-real FFTs (f16 in, f16 out)
// ---------------------------------------------------------------------------
__global__ __launch_bounds__(256) void fft_attn2(
    const f16* __restrict__ qkv, f16* __restrict__ outg)
{
    __shared__ f32x2 X[PAD(1023)+1], Y[PAD(1023)+1];
    const int tid = threadIdx.x;
    const size_t row0 = (size_t)blockIdx.x * 2;
    const f16* r1 = qkv + row0*QKVN;        // q1 | k1 | v1
    const f16* r2 = r1 + QKVN;              // q2 | k2 | v2

    f32x2 V1[4], V2[4], S1[4], S2[4];

    // ---- FFT(v1 + i*v2) -> V1, V2 in registers ----
    #pragma unroll
    for (int k = 0; k < 4; ++k) {
        const int i = tid + 256*k;
        f32x2 t; t.x = (float)r1[2048+i]; t.y = (float)r2[2048+i];
        X[PAD(i)] = t;
    }
    __syncthreads();
    fft1024r4(X, Y, tid);
    #pragma unroll
    for (int k = 0; k < 4; ++k) {
        const int f = tid + 256*k;
        const int g = (PD - f) & (PD-1);
        const f32x2 z1 = Y[PAD(f)], z2 = Y[PAD(g)];
        V1[k].x = 0.5f*(z1.x + z2.x); V1[k].y = 0.5f*(z1.y - z2.y);
        V2[k].x = 0.5f*(z1.y + z2.y); V2[k].y = 0.5f*(z2.x - z1.x);
    }

    // ---- FFT(q1 + i*k1) ; S1 = conj(K1*conj(Q1)*V1/32) ----
    #pragma unroll
    for (int k = 0; k < 4; ++k) {
        const int i = tid + 256*k;
        f32x2 t; t.x = (float)r1[i]; t.y = (float)r1[1024+i];
        X[PAD(i)] = t;
    }
    __syncthreads();   // fences the V-split reads of Y above
    fft1024r4(X, Y, tid);
    #pragma unroll
    for (int k = 0; k < 4; ++k) {
        const int f = tid + 256*k;
        const int g = (PD - f) & (PD-1);
        const f32x2 z1 = Y[PAD(f)], z2 = Y[PAD(g)];
        const float Qr = 0.5f*(z1.x + z2.x), Qi = 0.5f*(z1.y - z2.y);
        const float Kr = 0.5f*(z1.y + z2.y), Ki = 0.5f*(z2.x - z1.x);
        const float Pr = (Kr*Qr + Ki*Qi) * (1.f/32.f);
        const float Pi = (Ki*Qr - Kr*Qi) * (1.f/32.f);
        S1[k].x = Pr*V1[k].x - Pi*V1[k].y;
        S1[k].y = -(Pr*V1[k].y + Pi*V1[k].x);
    }

    // ---- FFT(q2 + i*k2) ; S2 = conj(K2*conj(Q2)*V2/32) ----
    #pragma unroll
    for (int k = 0; k < 4; ++k) {
        const int i = tid + 256*k;
        f32x2 t; t.x = (float)r2[i]; t.y = (float)r2[1024+i];
        X[PAD(i)] = t;
    }
    __syncthreads();
    fft1024r4(X, Y, tid);
    #pragma unroll
    for (int k = 0; k < 4; ++k) {
        const int f = tid + 256*k;
        const int g = (PD - f) & (PD-1);
        const f32x2 z1 = Y[PAD(f)], z2 = Y[PAD(g)];
        const float Qr = 0.5f*(z1.x + z2.x), Qi = 0.5f*(z1.y - z2.y);
        const float Kr = 0.5f*(z1.y + z2.y), Ki = 0.5f*(z2.x - z1.x);
        const float Pr = (Kr*Qr + Ki*Qi) * (1.f/32.f);
        const float Pi = (Ki*Qr - Kr*Qi) * (1.f/32.f);
        S2[k].x = Pr*V2[k].x - Pi*V2[k].y;
        S2[k].y = -(Pr*V2[k].y + Pi*V2[k].x);
    }

    // ---- packed inverse: FFT(S1 + i*S2) ----
    #pragma unroll
    for (int k = 0; k < 4; ++k) {
        const int f = tid + 256*k;
        f32x2 t; t.x = S1[k].x - S2[k].y; t.y = S1[k].y + S2[k].x;
        X[PAD(f)] = t;
    }
    __syncthreads();
    fft1024r4(X, Y, tid);
    f16* o1 = outg + row0*PD;
    f16* o2 = o1 + PD;
    #pragma unroll
    for (int k = 0; k < 4; ++k) {
        const int n = tid + 256*k;
        const f32x2 z = Y[PAD(n)];
        o1[n] = (f16)(z.x * (1.f/1024.f));
        o2[n] = (f16)(z.y * (1.f/1024.f));
    }
}

// ---------------------------------------------------------------------------
extern "C" void kernel_launch(void* const* d_in, const int* in_sizes, int n_in,
                              void* d_out, int out_size, void* d_ws, size_t ws_size,
                              hipStream_t stream)
{
    const float* x      = (const float*)d_in[0];
    const float* conv_w = (const float*)d_in[1];   // [L,E,1,K]
    const float* conv_b = (const float*)d_in[2];   // [L,E]
    const float* wq     = (const float*)d_in[3];   // [L,P,W]
    const float* bq     = (const float*)d_in[4];   // [L,P]
    const float* wk     = (const float*)d_in[5];
    const float* bk     = (const float*)d_in[6];
    const float* wv     = (const float*)d_in[7];
    const float* bv     = (const float*)d_in[8];
    const float* wo     = (const float*)d_in[9];   // [L,W,P]
    const float* bo     = (const float*)d_in[10];  // [L,W]

    // workspace layout (64 MiB), per-layer weight slots reused:
    //   0M..12M : wqkv16 f16 [3072, 2048]  (q rows 0-1023, k 1024-2047, v 2048-3071)
    //  12M..16M : wo16   f16 [2048, 1024]
    //  16M..40M : qkvbuf f16 [4096, 3072]  (row-interleaved q|k|v)
    //  40M..56M : xc16   f16 [4096, 2048]  (first 8 MiB also aliased wvr16 [4096,1024])
    //  56M..72M : xmid   f16 [4096, 2048]
    char* ws = (char*)d_ws;
    const size_t MB = 1024*1024;
    f16*   wqkv16 = (f16*)(ws);
    f16*   wo16   = (f16*)(ws + 12*MB);
    f16*   qkvbuf = (f16*)(ws + 16*MB);
    f16*   xc16   = (f16*)(ws + 40*MB);
    f16*   xmid   = (f16*)(ws + 56*MB);
    f16*   wvr16  = xc16;   // alias: xc dead once the QKV GEMM completes

    for (int l = 0; l < LN; ++l) {
        // convert this layer's 4 weight tensors in one dispatch
        cvt_layer<<<dim3(4*NWL/4/256), dim3(256), 0, stream>>>(
            wq + (size_t)l*NWL, wk + (size_t)l*NWL, wv + (size_t)l*NWL, wo + (size_t)l*NWL,
            wqkv16, wo16);

        if (l == 0)
            conv_moe<float><<<dim3(MROWS), dim3(256), 0, stream>>>(
                x, conv_w, conv_b, xc16);
        else
            conv_moe<f16><<<dim3(MROWS), dim3(256), 0, stream>>>(
                xmid, conv_w + (size_t)l*ED*KSZ, conv_b + (size_t)l*ED, xc16);

        // qkv = xc @ wqkv^T + [bq|bk|bv]   (M=4096, K=2048, N=3072), f16 out
        // 256x256 4-barrier pipelined GEMM: grid 16x12 = 192 blocks
        gemm256<<<dim3((MROWS/256)*(QKVN/256)), dim3(512), 0, stream>>>(
            xc16, wqkv16,
            bq + (size_t)l*PD, bk + (size_t)l*PD, bv + (size_t)l*PD,
            qkvbuf, WD, QKVN);

        fft_attn2<<<dim3(MROWS/2), dim3(256), 0, stream>>>(qkvbuf, wvr16);

        // xnext = wvr @ wo^T + bo  (M=4096, K=1024, N=2048)
        if (l == LN-1)
            gemm_f16<float><<<dim3(MROWS/128, WD/128), dim3(256), 0, stream>>>(
                wvr16, wo16,
                bo + (size_t)l*WD, bo + (size_t)l*WD + PD, bo + (size_t)l*WD + PD,
                (float*)d_out, PD, WD);
        else
            gemm_f16<f16><<<dim3(MROWS/128, WD/128), dim3(256), 0, stream>>>(
                wvr16, wo16,
                bo + (size_t)l*WD, bo + (size_t)l*WD + PD, bo + (size_t)l*WD + PD,
                xmid, PD, WD);
    }
}

// Round 3
// 402.459 us; speedup vs baseline: 1.0399x; 1.0067x over previous
//
#include <hip/hip_runtime.h>
#include <hip/hip_bf16.h>

// Problem constants (FEDformerEncoder): BS=32 CNT=128 W=2048 P=1024 E=8 K=25 L=2
#define BSZ 32
#define CNTS 128
#define WD 2048
#define PD 1024
#define ED 8
#define KSZ 25
#define LN 2
#define MROWS (BSZ*CNTS)   // 4096
#define QKVN (3*PD)        // 3072
#define NWL (PD*WD)        // 2M elements per weight tensor per layer

typedef _Float16 f16;
typedef __attribute__((ext_vector_type(8))) _Float16 f16x8;  // 8 f16 = 4 VGPRs
typedef __attribute__((ext_vector_type(4))) float f32x4;
typedef __attribute__((ext_vector_type(2))) float f32x2;

#define PI_F 3.14159265358979323846f
// LDS physical index padding for the FFT (+1 float2 per 32 elements)
#define PAD(a) ((a) + ((a) >> 5))

// ---------------------------------------------------------------------------
// Per-layer weight conversion, one dispatch: wq|wk|wv -> wqkv16 packed, wo -> wo16.
// ---------------------------------------------------------------------------
__global__ __launch_bounds__(256) void cvt_layer(
    const float* __restrict__ wq, const float* __restrict__ wk,
    const float* __restrict__ wv, const float* __restrict__ wo,
    f16* __restrict__ wqkv16, f16* __restrict__ wo16)
{
    const int i = (blockIdx.x * 256 + threadIdx.x) * 4;
    const float* src;
    f16* dst;
    if (i < 3*NWL) {
        dst = wqkv16 + i;
        src = (i < NWL) ? wq + i : (i < 2*NWL) ? wk + (i - NWL) : wv + (i - 2*NWL);
    } else {
        dst = wo16 + (i - 3*NWL);
        src = wo + (i - 3*NWL);
    }
    const float4 v = *(const float4*)src;
    f16 o[4];
    o[0] = (f16)v.x; o[1] = (f16)v.y; o[2] = (f16)v.z; o[3] = (f16)v.w;
    *(ushort4*)dst = *(const ushort4*)o;
}

// ---------------------------------------------------------------------------
// MoE conv: mean over E of conv1d(x, w_e)+b_e == conv1d(x, mean_e w_e)+mean_e b_e
// ---------------------------------------------------------------------------
template<typename IT>
__global__ __launch_bounds__(256) void conv_moe(
    const IT* __restrict__ xin,      // [4096, 2048]
    const float* __restrict__ cw,    // [E, K] layer slice
    const float* __restrict__ cb,    // [E]
    f16* __restrict__ xo)            // [4096, 2048] f16
{
    __shared__ float srow[WD];
    __shared__ float swb[KSZ];
    __shared__ float sbb;
    const int tid = threadIdx.x;
    const size_t row = blockIdx.x;
    if (tid < KSZ) {
        float s = 0.f;
        for (int e = 0; e < ED; ++e) s += cw[e*KSZ + tid];
        swb[tid] = s * (1.f/ED);
    }
    if (tid == 32) {
        float s = 0.f;
        for (int e = 0; e < ED; ++e) s += cb[e];
        sbb = s * (1.f/ED);
    }
    const IT* xr = xin + row*WD;
    for (int i = tid; i < WD; i += 256) srow[i] = (float)xr[i];
    __syncthreads();
    const float bb = sbb;
    for (int t0 = 0; t0 < WD; t0 += 256) {
        const int t = t0 + tid;
        float acc = bb;
        #pragma unroll
        for (int k = 0; k < KSZ; ++k) {
            const int idx = t + k - (KSZ/2);
            const float xv = (idx >= 0 && idx < WD) ? srow[idx] : 0.f;
            acc = fmaf(xv, swb[k], acc);
        }
        xo[row*WD + t] = (f16)acc;
    }
}

// ---------------------------------------------------------------------------
// f16 MFMA GEMM, B^T layout, 128x128 tile (verified m97-class structure).
// Kept for the out-projection GEMM (M=4096, K=1024, N=2048 -> 512 blocks).
// ---------------------------------------------------------------------------
template<typename OT>
__global__ __launch_bounds__(256, 2) void gemm_f16(
    const f16* __restrict__ A,   // [M, K]
    const f16* __restrict__ B,   // [N, K]
    const float* __restrict__ c0, const float* __restrict__ c1, const float* __restrict__ c2,
    OT* __restrict__ out,        // [M, N]
    const int K, const int N)
{
    __shared__ f16 sA[128*64];
    __shared__ f16 sB[128*64];
    const int tid  = threadIdx.x;
    const int m0   = blockIdx.x * 128;
    const int n0   = blockIdx.y * 128;
    const int lane = tid & 63;
    const int wave = tid >> 6;
    const int wm   = (wave >> 1) * 64;
    const int wn   = (wave & 1) * 64;
    const int quad = lane >> 4;
    const int r16  = lane & 15;

    f32x4 acc[4][4] = {};

    int aoff[4];
    #pragma unroll
    for (int t = 0; t < 4; ++t) {
        const int s = tid + 256*t;
        const int row = s >> 3;
        const int sc8 = ((s & 7) ^ (row & 7)) * 8;
        aoff[t] = row * K + sc8;
    }

    int aBase[4], aXor[4], bBase[4], bXor[4];
    #pragma unroll
    for (int i = 0; i < 4; ++i) {
        const int ra = wm + i*16 + r16;
        aBase[i] = ra << 3; aXor[i] = ra & 7;
        const int rb = wn + i*16 + r16;
        bBase[i] = rb << 3; bXor[i] = rb & 7;
    }

    const size_t mK = (size_t)m0 * K;
    const size_t nK = (size_t)n0 * K;

    for (int kb = 0; kb < K; kb += 64) {
        #pragma unroll
        for (int t = 0; t < 4; ++t) {
            const int s = tid + 256*t;
            __builtin_amdgcn_global_load_lds(
                (const __attribute__((address_space(1))) unsigned int*)(A + mK + aoff[t] + kb),
                (__attribute__((address_space(3))) unsigned int*)&sA[s*8], 16, 0, 0);
            __builtin_amdgcn_global_load_lds(
                (const __attribute__((address_space(1))) unsigned int*)(B + nK + aoff[t] + kb),
                (__attribute__((address_space(3))) unsigned int*)&sB[s*8], 16, 0, 0);
        }
        __syncthreads();

        #pragma unroll
        for (int ks = 0; ks < 2; ++ks) {
            const int c = ks*4 + quad;
            f16x8 af[4], bfm[4];
            #pragma unroll
            for (int i = 0; i < 4; ++i)
                af[i] = *(const f16x8*)&sA[(aBase[i] | (c ^ aXor[i])) * 8];
            #pragma unroll
            for (int j = 0; j < 4; ++j)
                bfm[j] = *(const f16x8*)&sB[(bBase[j] | (c ^ bXor[j])) * 8];
            #pragma unroll
            for (int i = 0; i < 4; ++i)
                #pragma unroll
                for (int j = 0; j < 4; ++j)
                    acc[i][j] = __builtin_amdgcn_mfma_f32_16x16x32_f16(af[i], bfm[j], acc[i][j], 0, 0, 0);
        }
        __syncthreads();
    }

    #pragma unroll
    for (int j = 0; j < 4; ++j) {
        const int col = n0 + wn + j*16 + r16;
        const float bv = (col < 1024) ? c0[col] : (col < 2048) ? c1[col-1024] : c2[col-2048];
        #pragma unroll
        for (int i = 0; i < 4; ++i) {
            #pragma unroll
            for (int r = 0; r < 4; ++r) {
                const int rowg = m0 + wm + i*16 + quad*4 + r;
                out[(size_t)rowg*N + col] = (OT)(acc[i][j][r] + bv);
            }
        }
    }
}

// ---------------------------------------------------------------------------
// 256x192 pipelined f16 GEMM for QKV (M=4096, K=2048, N=3072):
// grid 16m x 16n = 256 blocks -> EVERY CU gets a block (vs 192 at 256x256).
// 512 thr = 8 waves (2M x 4N), per-wave output 128x48 (3 n-frags).
// LDS 112 KiB: sA 2buf x 2halves x [128x64], sB 2buf x 3pieces x [64x64],
// XOR-chunk swizzled (slot s holds chunk (s&7)^(row&7) of row s>>3).
// 4-barrier schedule, counted waits; loads/thread/iter = 14 (A 4x2, B 6x1):
//   T0 win: P1 A1h0 | P2 A1h1 | P3 B0'p0 B0'p1 | P4 B0'p2  -> vmcnt(3), B2
//   T1 win: P5 A0'h0| P6 A0'h1| P7 B1'p0 B1'p1 | P8 B1'p2  -> vmcnt(3), B4
// At B2 in-flight = B1'prev(3)+A1(4)+B0'(3)=10, need oldest 7 -> vmcnt(3).
// Last-iter B2 drains vmcnt(0) (no B0'/A0' staged).
// ---------------------------------------------------------------------------
__global__ __launch_bounds__(512, 2) void gemm192(
    const f16* __restrict__ A,   // [M, K]
    const f16* __restrict__ B,   // [N, K]
    const float* __restrict__ c0, const float* __restrict__ c1, const float* __restrict__ c2,
    f16* __restrict__ out,       // [M, N]
    const int K, const int N)
{
    __shared__ __align__(16) f16 sA[2][2][128*64];
    __shared__ __align__(16) f16 sB[2][3][64*64];

    const int tid  = threadIdx.x;
    const int lane = tid & 63;
    const int wave = tid >> 6;
    const int wr   = wave >> 2;          // 0..1 : A 128-row half
    const int wc   = wave & 3;           // 0..3 : 48-col block
    const int quad = lane >> 4;
    const int r16  = lane & 15;
    const int xrA  = r16 & 7;            // A read-side XOR key

    // 2D XCD chunking: grid 16m x 16n = 256 blocks; XCD owns 4m x 8n (32 blocks)
    const int orig = blockIdx.x;
    const int xcd  = orig & 7;
    const int loc  = orig >> 3;          // 0..31
    const int mt   = (xcd >> 1) * 4 + (loc & 3);
    const int nt   = (xcd & 1) * 8 + (loc >> 2);
    const int m0   = mt * 256;
    const int n0   = nt * 192;

    f32x4 acc[8][3] = {};
    f16x8 bf[3][2];
    f16x8 aX0, aX1, aX2, aX3, aY0, aY1, aY2, aY3, aZ0, aZ1, aZ2, aZ3;

    // A staging: 2 slots/thread per 16 KiB half; B staging: 1 slot/thread per 8 KiB piece
    int soffA[2];
    #pragma unroll
    for (int t = 0; t < 2; ++t) {
        const int s = tid + 512*t;
        const int row = s >> 3;
        soffA[t] = row * K + (((s & 7) ^ (row & 7)) * 8);
    }
    int soffB;
    {
        const int row = tid >> 3;
        soffB = row * K + (((tid & 7) ^ (row & 7)) * 8);
    }

    // B read-side per-frag constants: rb = wc*48 + j*16 + r16
    int bPiece[3], bBase[3], bXor[3];
    #pragma unroll
    for (int j = 0; j < 3; ++j) {
        const int rb = wc*48 + j*16 + r16;
        bPiece[j] = rb >> 6;
        bBase[j]  = (rb & 63) << 3;
        bXor[j]   = rb & 7;
    }

    const f16* Abase[2] = { A + (size_t)m0 * K, A + (size_t)(m0 + 128) * K };
    const f16* Bp[3]    = { B + (size_t)n0 * K, B + (size_t)(n0 + 64) * K,
                            B + (size_t)(n0 + 128) * K };

    #define STAGE_A(BUF, HALF, GOFF)                                              \
      { _Pragma("unroll") for (int t = 0; t < 2; ++t) {                           \
          __builtin_amdgcn_global_load_lds(                                       \
            (const __attribute__((address_space(1))) unsigned int*)(Abase[HALF] + soffA[t] + (GOFF)), \
            (__attribute__((address_space(3))) unsigned int*)&sA[BUF][HALF][(tid + 512*t)*8], \
            16, 0, 0); } }

    #define STAGE_B(BUF, PIECE, GOFF)                                             \
      { __builtin_amdgcn_global_load_lds(                                         \
          (const __attribute__((address_space(1))) unsigned int*)(Bp[PIECE] + soffB + (GOFF)), \
          (__attribute__((address_space(3))) unsigned int*)&sB[BUF][PIECE][tid*8], \
          16, 0, 0); }

    #define LDA(BUF, ROW, C) \
      (*(const f16x8*)&sA[BUF][wr][ (((ROW) << 3) + ((C) ^ xrA)) * 8 ])

    #define LDB(BUF, J, C) \
      (*(const f16x8*)&sB[BUF][bPiece[J]][ (bBase[J] + ((C) ^ bXor[J])) * 8 ])

    #define READ_BF(BUF)                                                          \
      { _Pragma("unroll") for (int j = 0; j < 3; ++j) {                           \
          bf[j][0] = LDB(BUF, j, quad);                                           \
          bf[j][1] = LDB(BUF, j, 4 + quad);                                       \
        } }

    #define READ_A(BUF, Q, D0, D1, D2, D3)                                        \
      D0 = LDA(BUF, (2*(Q))*16   + r16, quad);                                    \
      D1 = LDA(BUF, (2*(Q))*16   + r16, 4 + quad);                                \
      D2 = LDA(BUF, (2*(Q)+1)*16 + r16, quad);                                    \
      D3 = LDA(BUF, (2*(Q)+1)*16 + r16, 4 + quad);

    #define MFMA_Q(Q, D0, D1, D2, D3)                                             \
      __builtin_amdgcn_s_setprio(1);                                              \
      { _Pragma("unroll") for (int jj = 0; jj < 3; ++jj) {                        \
          acc[2*(Q)][jj]   = __builtin_amdgcn_mfma_f32_16x16x32_f16(D0, bf[jj][0], acc[2*(Q)][jj],   0,0,0); \
          acc[2*(Q)+1][jj] = __builtin_amdgcn_mfma_f32_16x16x32_f16(D2, bf[jj][0], acc[2*(Q)+1][jj], 0,0,0); \
        } }                                                                       \
      { _Pragma("unroll") for (int jj = 0; jj < 3; ++jj) {                        \
          acc[2*(Q)][jj]   = __builtin_amdgcn_mfma_f32_16x16x32_f16(D1, bf[jj][1], acc[2*(Q)][jj],   0,0,0); \
          acc[2*(Q)+1][jj] = __builtin_amdgcn_mfma_f32_16x16x32_f16(D3, bf[jj][1], acc[2*(Q)+1][jj], 0,0,0); \
        } }                                                                       \
      __builtin_amdgcn_s_setprio(0);

    #define LGKM(n) asm volatile("s_waitcnt lgkmcnt(" #n ")" ::: "memory");       \
                    __builtin_amdgcn_sched_barrier(0);
    #define VMC(n)  asm volatile("s_waitcnt vmcnt(" #n ")" ::: "memory");
    #define BAR()   __builtin_amdgcn_s_barrier();

    // prologue: B-buf0 (3), A-buf0 (4), B-buf1 (3) -> 10 loads; need oldest 7
    STAGE_B(0, 0, 0); STAGE_B(0, 1, 0); STAGE_B(0, 2, 0);
    STAGE_A(0, 0, 0); STAGE_A(0, 1, 0);
    STAGE_B(1, 0, 64); STAGE_B(1, 1, 64); STAGE_B(1, 2, 64);
    VMC(3)
    BAR()

    const int NIT = K >> 7;   // two K-tiles (BK=64) per iteration
    for (int it = 0; it < NIT; ++it) {
        const bool kl = (it == NIT - 1);
        const int kb1 = (2*it + 1) * 64;
        const int kb2 = kb1 + 64;
        const int kb3 = kb1 + 128;

        // ---------- K-tile 2it : buf0 ----------
        STAGE_A(1, 0, kb1);                                    // P1
        READ_BF(0)
        READ_A(0, 0, aX0, aX1, aX2, aX3)
        LGKM(0)
        MFMA_Q(0, aX0, aX1, aX2, aX3)
        BAR()                                                  // B1
        STAGE_A(1, 1, kb1);                                    // P2
        READ_A(0, 1, aY0, aY1, aY2, aY3)
        READ_A(0, 2, aZ0, aZ1, aZ2, aZ3)
        LGKM(4)
        MFMA_Q(1, aY0, aY1, aY2, aY3)
        if (!kl) { STAGE_B(0, 0, kb2); STAGE_B(0, 1, kb2); }   // P3
        READ_A(0, 3, aX0, aX1, aX2, aX3)
        LGKM(4)
        MFMA_Q(2, aZ0, aZ1, aZ2, aZ3)
        if (!kl) { STAGE_B(0, 2, kb2); }                       // P4
        LGKM(0)
        MFMA_Q(3, aX0, aX1, aX2, aX3)
        if (!kl) { VMC(3) } else { VMC(0) }
        BAR()                                                  // B2

        // ---------- K-tile 2it+1 : buf1 ----------
        if (!kl) STAGE_A(0, 0, kb2);                           // P5
        READ_BF(1)
        READ_A(1, 0, aX0, aX1, aX2, aX3)
        LGKM(0)
        MFMA_Q(0, aX0, aX1, aX2, aX3)
        BAR()                                                  // B3
        if (!kl) STAGE_A(0, 1, kb2);                           // P6
        READ_A(1, 1, aY0, aY1, aY2, aY3)
        READ_A(1, 2, aZ0, aZ1, aZ2, aZ3)
        LGKM(4)
        MFMA_Q(1, aY0, aY1, aY2, aY3)
        if (!kl) { STAGE_B(1, 0, kb3); STAGE_B(1, 1, kb3); }   // P7
        READ_A(1, 3, aX0, aX1, aX2, aX3)
        LGKM(4)
        MFMA_Q(2, aZ0, aZ1, aZ2, aZ3)
        if (!kl) { STAGE_B(1, 2, kb3); }                       // P8
        LGKM(0)
        MFMA_Q(3, aX0, aX1, aX2, aX3)
        if (!kl) { VMC(3) }
        BAR()                                                  // B4
    }

    // epilogue: C/D mapping (16x16x32): col = lane&15, row = quad*4 + r
    #pragma unroll
    for (int j = 0; j < 3; ++j) {
        const int col = n0 + wc*48 + j*16 + r16;
        const float bv = (col < 1024) ? c0[col] : (col < 2048) ? c1[col-1024] : c2[col-2048];
        #pragma unroll
        for (int mi = 0; mi < 8; ++mi) {
            #pragma unroll
            for (int r = 0; r < 4; ++r) {
                const int rowg = m0 + wr*128 + mi*16 + quad*4 + r;
                out[(size_t)rowg*N + col] = (f16)(acc[mi][j][r] + bv);
            }
        }
    }

    #undef STAGE_A
    #undef STAGE_B
    #undef LDA
    #undef LDB
    #undef READ_BF
    #undef READ_A
    #undef MFMA_Q
    #undef LGKM
    #undef VMC
    #undef BAR
}

// ---------------------------------------------------------------------------
// Stockham radix-4 DIF FFT, 1024 points, 256 threads, interleaved f32x2 in LDS
// ---------------------------------------------------------------------------
__device__ inline void fft1024r4(f32x2* x, f32x2* y, const int tid)
{
    f32x2* src = x;
    f32x2* dst = y;
    #pragma unroll
    for (int st = 0; st < 5; ++st) {
        const int ls = 2*st;
        const int s  = 1 << ls;
        const int p  = tid >> ls;
        const int q  = tid & (s - 1);
        const float invn = 1.f / (float)(1024 >> ls);
        const f32x2 a = src[PAD(tid)];
        const f32x2 b = src[PAD(tid + 256)];
        const f32x2 c = src[PAD(tid + 512)];
        const f32x2 d = src[PAD(tid + 768)];
        float ws, wc;
        __sincosf(-2.f*PI_F * (float)p * invn, &ws, &wc);
        const float apcx = a.x + c.x, apcy = a.y + c.y;
        const float amcx = a.x - c.x, amcy = a.y - c.y;
        const float bpdx = b.x + d.x, bpdy = b.y + d.y;
        const float bmdx = b.x - d.x, bmdy = b.y - d.y;
        f32x2 y0; y0.x = apcx + bpdx; y0.y = apcy + bpdy;
        const float t1x = amcx + bmdy, t1y = amcy - bmdx;   // amc - i*bmd
        const float t2x = apcx - bpdx, t2y = apcy - bpdy;
        const float t3x = amcx - bmdy, t3y = amcy + bmdx;   // amc + i*bmd
        const float w2x = wc*wc - ws*ws, w2y = 2.f*wc*ws;
        const float w3x = w2x*wc - w2y*ws, w3y = w2x*ws + w2y*wc;
        f32x2 y1; y1.x = wc*t1x - ws*t1y;   y1.y = wc*t1y + ws*t1x;
        f32x2 y2; y2.x = w2x*t2x - w2y*t2y; y2.y = w2x*t2y + w2y*t2x;
        f32x2 y3; y3.x = w3x*t3x - w3y*t3y; y3.y = w3x*t3y + w3y*t3x;
        const int base = q + ((p * s) << 2);
        dst[PAD(base)]       = y0;
        dst[PAD(base + s)]   = y1;
        dst[PAD(base + 2*s)] = y2;
        dst[PAD(base + 3*s)] = y3;
        __syncthreads();
        f32x2* t = src; src = dst; dst = t;
    }
}

// ---------------------------------------------------------------------------
// FFT-domain attention, two rows per block, packed-real FFTs (f16 in, f16 out)
// ---------------------------------------------------------------------------
__global__ __launch_bounds__(256) void fft_attn2(
    const f16* __restrict__ qkv, f16* __restrict__ outg)
{
    __shared__ f32x2 X[PAD(1023)+1], Y[PAD(1023)+1];
    const int tid = threadIdx.x;
    const size_t row0 = (size_t)blockIdx.x * 2;
    const f16* r1 = qkv + row0*QKVN;        // q1 | k1 | v1
    const f16* r2 = r1 + QKVN;              // q2 | k2 | v2

    f32x2 V1[4], V2[4], S1[4], S2[4];

    // ---- FFT(v1 + i*v2) -> V1, V2 in registers ----
    #pragma unroll
    for (int k = 0; k < 4; ++k) {
        const int i = tid + 256*k;
        f32x2 t; t.x = (float)r1[2048+i]; t.y = (float)r2[2048+i];
        X[PAD(i)] = t;
    }
    __syncthreads();
    fft1024r4(X, Y, tid);
    #pragma unroll
    for (int k = 0; k < 4; ++k) {
        const int f = tid + 256*k;
        const int g = (PD - f) & (PD-1);
        const f32x2 z1 = Y[PAD(f)], z2 = Y[PAD(g)];
        V1[k].x = 0.5f*(z1.x + z2.x); V1[k].y = 0.5f*(z1.y - z2.y);
        V2[k].x = 0.5f*(z1.y + z2.y); V2[k].y = 0.5f*(z2.x - z1.x);
    }

    // ---- FFT(q1 + i*k1) ; S1 = conj(K1*conj(Q1)*V1/32) ----
    #pragma unroll
    for (int k = 0; k < 4; ++k) {
        const int i = tid + 256*k;
        f32x2 t; t.x = (float)r1[i]; t.y = (float)r1[1024+i];
        X[PAD(i)] = t;
    }
    __syncthreads();   // fences the V-split reads of Y above
    fft1024r4(X, Y, tid);
    #pragma unroll
    for (int k = 0; k < 4; ++k) {
        const int f = tid + 256*k;
        const int g = (PD - f) & (PD-1);
        const f32x2 z1 = Y[PAD(f)], z2 = Y[PAD(g)];
        const float Qr = 0.5f*(z1.x + z2.x), Qi = 0.5f*(z1.y - z2.y);
        const float Kr = 0.5f*(z1.y + z2.y), Ki = 0.5f*(z2.x - z1.x);
        const float Pr = (Kr*Qr + Ki*Qi) * (1.f/32.f);
        const float Pi = (Ki*Qr - Kr*Qi) * (1.f/32.f);
        S1[k].x = Pr*V1[k].x - Pi*V1[k].y;
        S1[k].y = -(Pr*V1[k].y + Pi*V1[k].x);
    }

    // ---- FFT(q2 + i*k2) ; S2 = conj(K2*conj(Q2)*V2/32) ----
    #pragma unroll
    for (int k = 0; k < 4; ++k) {
        const int i = tid + 256*k;
        f32x2 t; t.x = (float)r2[i]; t.y = (float)r2[1024+i];
        X[PAD(i)] = t;
    }
    __syncthreads();
    fft1024r4(X, Y, tid);
    #pragma unroll
    for (int k = 0; k < 4; ++k) {
        const int f = tid + 256*k;
        const int g = (PD - f) & (PD-1);
        const f32x2 z1 = Y[PAD(f)], z2 = Y[PAD(g)];
        const float Qr = 0.5f*(z1.x + z2.x), Qi = 0.5f*(z1.y - z2.y);
        const float Kr = 0.5f*(z1.y + z2.y), Ki = 0.5f*(z2.x - z1.x);
        const float Pr = (Kr*Qr + Ki*Qi) * (1.f/32.f);
        const float Pi = (Ki*Qr - Kr*Qi) * (1.f/32.f);
        S2[k].x = Pr*V2[k].x - Pi*V2[k].y;
        S2[k].y = -(Pr*V2[k].y + Pi*V2[k].x);
    }

    // ---- packed inverse: FFT(S1 + i*S2) ----
    #pragma unroll
    for (int k = 0; k < 4; ++k) {
        const int f = tid + 256*k;
        f32x2 t; t.x = S1[k].x - S2[k].y; t.y = S1[k].y + S2[k].x;
        X[PAD(f)] = t;
    }
    __syncthreads();
    fft1024r4(X, Y, tid);
    f16* o1 = outg + row0*PD;
    f16* o2 = o1 + PD;
    #pragma unroll
    for (int k = 0; k < 4; ++k) {
        const int n = tid + 256*k;
        const f32x2 z = Y[PAD(n)];
        o1[n] = (f16)(z.x * (1.f/1024.f));
        o2[n] = (f16)(z.y * (1.f/1024.f));
    }
}

// ---------------------------------------------------------------------------
extern "C" void kernel_launch(void* const* d_in, const int* in_sizes, int n_in,
                              void* d_out, int out_size, void* d_ws, size_t ws_size,
                              hipStream_t stream)
{
    const float* x      = (const float*)d_in[0];
    const float* conv_w = (const float*)d_in[1];   // [L,E,1,K]
    const float* conv_b = (const float*)d_in[2];   // [L,E]
    const float* wq     = (const float*)d_in[3];   // [L,P,W]
    const float* bq     = (const float*)d_in[4];   // [L,P]
    const float* wk     = (const float*)d_in[5];
    const float* bk     = (const float*)d_in[6];
    const float* wv     = (const float*)d_in[7];
    const float* bv     = (const float*)d_in[8];
    const float* wo     = (const float*)d_in[9];   // [L,W,P]
    const float* bo     = (const float*)d_in[10];  // [L,W]

    // workspace layout (64 MiB), per-layer weight slots reused:
    //   0M..12M : wqkv16 f16 [3072, 2048]  (q rows 0-1023, k 1024-2047, v 2048-3071)
    //  12M..16M : wo16   f16 [2048, 1024]
    //  16M..40M : qkvbuf f16 [4096, 3072]  (row-interleaved q|k|v)
    //  40M..56M : xc16   f16 [4096, 2048]  (first 8 MiB also aliased wvr16 [4096,1024])
    //  56M..72M : xmid   f16 [4096, 2048]
    char* ws = (char*)d_ws;
    const size_t MB = 1024*1024;
    f16*   wqkv16 = (f16*)(ws);
    f16*   wo16   = (f16*)(ws + 12*MB);
    f16*   qkvbuf = (f16*)(ws + 16*MB);
    f16*   xc16   = (f16*)(ws + 40*MB);
    f16*   xmid   = (f16*)(ws + 56*MB);
    f16*   wvr16  = xc16;   // alias: xc dead once the QKV GEMM completes

    for (int l = 0; l < LN; ++l) {
        // convert this layer's 4 weight tensors in one dispatch
        cvt_layer<<<dim3(4*NWL/4/256), dim3(256), 0, stream>>>(
            wq + (size_t)l*NWL, wk + (size_t)l*NWL, wv + (size_t)l*NWL, wo + (size_t)l*NWL,
            wqkv16, wo16);

        if (l == 0)
            conv_moe<float><<<dim3(MROWS), dim3(256), 0, stream>>>(
                x, conv_w, conv_b, xc16);
        else
            conv_moe<f16><<<dim3(MROWS), dim3(256), 0, stream>>>(
                xmid, conv_w + (size_t)l*ED*KSZ, conv_b + (size_t)l*ED, xc16);

        // qkv = xc @ wqkv^T + [bq|bk|bv]   (M=4096, K=2048, N=3072), f16 out
        // 256x192 pipelined GEMM: grid 16x16 = 256 blocks (all CUs busy)
        gemm192<<<dim3((MROWS/256)*(QKVN/192)), dim3(512), 0, stream>>>(
            xc16, wqkv16,
            bq + (size_t)l*PD, bk + (size_t)l*PD, bv + (size_t)l*PD,
            qkvbuf, WD, QKVN);

        fft_attn2<<<dim3(MROWS/2), dim3(256), 0, stream>>>(qkvbuf, wvr16);

        // xnext = wvr @ wo^T + bo  (M=4096, K=1024, N=2048)
        if (l == LN-1)
            gemm_f16<float><<<dim3(MROWS/128, WD/128), dim3(256), 0, stream>>>(
                wvr16, wo16,
                bo + (size_t)l*WD, bo + (size_t)l*WD + PD, bo + (size_t)l*WD + PD,
                (float*)d_out, PD, WD);
        else
            gemm_f16<f16><<<dim3(MROWS/128, WD/128), dim3(256), 0, stream>>>(
                wvr16, wo16,
                bo + (size_t)l*WD, bo + (size_t)l*WD + PD, bo + (size_t)l*WD + PD,
                xmid, PD, WD);
    }
}